// Round 9
// baseline (843.019 us; speedup 1.0000x reference)
//
#include <hip/hip_runtime.h>
#include <hip/hip_fp16.h>
#include <stdint.h>

// ---------------------------------------------------------------------------
// GNN forward: GCN -> SAGE(+res) -> SAGE(+res) -> lin -> GCN
// R2: bounded unroll fixed GEMM spill.  R3/R4: wide gather + fp16 mirror.
// R5: bucket scatter.  R6: work-steal regressed.  R7: 8x8 gather.
// R8: wave-agg ballot (LDS conflicts 472K->1K, but k_bucket unchanged ->
//     random global deg atomics were the real cost; aggs are L3-latency-bound
//     because the 12.8MB gather table exceeds the 4MB per-XCD L2).
// R9a: 4-quarter aggregation — features split into 4 passes of D=16; quarter
//      table = 3.2MB FITS per-XCD L2. hh + agg outputs pass-major [4][n][16].
//      One launch per stage; p = bid/nq gives temporal phase separation.
//      2 nodes/wave x 16 slots -> 32 rows per vmem instr.
// R9b: slice-local LDS CSR finish: k_deg3/k_fill3 = 1 block/slice with 50KB
//      LDS hist/cursors; NO global atomics; csr writes stay in one L2 window.
//      deg atomics removed from k_bucket.
// ---------------------------------------------------------------------------

typedef unsigned long long ull;
typedef unsigned short ushort8v __attribute__((ext_vector_type(8)));

#define NSL 8
#define MAXSL 12544          // >= ceil(100000/8); 50176B LDS
#define BKT_BLOCKS 1024

__device__ __forceinline__ void fma4(float4& a, float s, const float4& w){
  a.x = fmaf(s, w.x, a.x);
  a.y = fmaf(s, w.y, a.y);
  a.z = fmaf(s, w.z, a.z);
  a.w = fmaf(s, w.w, a.w);
}

__device__ __forceinline__ ushort4 pack_h4(float4 v){
  ushort4 u;
  u.x = __half_as_ushort(__float2half(v.x));
  u.y = __half_as_ushort(__float2half(v.y));
  u.z = __half_as_ushort(__float2half(v.z));
  u.w = __half_as_ushort(__float2half(v.w));
  return u;
}

__device__ __forceinline__ ull slice_group(bool act, int s){
  ull bm = __ballot(act);
  ull m0 = __ballot(s & 1);
  ull m1 = __ballot(s & 2);
  ull m2 = __ballot(s & 4);
  ull g = bm;
  g &= (s & 1) ? m0 : ~m0;
  g &= (s & 2) ? m1 : ~m1;
  g &= (s & 4) ? m2 : ~m2;
  return g;
}

// ---------------- CSR build ----------------
// k_bucket: scatter packed (src<<32|dst) into 8 dst-slice buckets.
// (deg counting moved to k_deg3 — the fused random global atomics were the
//  dominant cost in R7/R8.)

__global__ __launch_bounds__(256) void k_bucket(const int* __restrict__ src,
                                                const int* __restrict__ dst,
                                                ull* __restrict__ bkt,
                                                int* __restrict__ bcnt,
                                                int E, int SL, int cap){
  __shared__ int hist[NSL];
  __shared__ int cur[NSL];
  int t = threadIdx.x;
  int lane = t & 63;
  int chunk = (E + BKT_BLOCKS - 1) / BKT_BLOCKS;
  int e0 = blockIdx.x * chunk;
  int e1 = min(E, e0 + chunk);
  if (t < NSL) hist[t] = 0;
  __syncthreads();
  for (int base = e0; base < e1; base += 256){
    int e = base + t;
    bool act = e < e1;
    int s = 0;
    if (act) s = dst[e] / SL;
    ull g = slice_group(act, s);
    if (act && lane == (__ffsll((long long)g) - 1))
      atomicAdd(&hist[s], __popcll(g));
  }
  __syncthreads();
  if (t < NSL){
    int h = hist[t];
    cur[t] = h ? atomicAdd(&bcnt[t], h) : 0;
  }
  __syncthreads();
  for (int base = e0; base < e1; base += 256){
    int e = base + t;
    bool act = e < e1;
    int s = 0; ull pk = 0;
    if (act){
      int d = dst[e];
      s = d / SL;
      pk = ((ull)(unsigned)src[e] << 32) | (unsigned)d;
    }
    ull g = slice_group(act, s);
    int leader = __ffsll((long long)g) - 1;
    int rank = __popcll(g & ((1ull << lane) - 1));
    int bs = 0;
    if (act && lane == leader) bs = atomicAdd(&cur[s], __popcll(g));
    bs = __shfl(bs, leader);
    if (act){
      int pos = bs + rank;
      if (pos < cap) bkt[(size_t)s * cap + pos] = pk;
    }
  }
}

// one block per slice: LDS histogram -> deg (no global atomics)
__global__ __launch_bounds__(256) void k_deg3(const ull* __restrict__ bkt,
                                              const int* __restrict__ bcnt,
                                              int* __restrict__ deg,
                                              int cap, int SL, int n){
  __shared__ int hist[MAXSL];
  int s = blockIdx.x;
  int lo = s * SL;
  int m = n - lo; if (m > SL) m = SL; if (m < 0) m = 0;
  for (int i = threadIdx.x; i < m; i += 256) hist[i] = 0;
  __syncthreads();
  int cnt = min(bcnt[s], cap);
  const ull* b = bkt + (size_t)s * cap;
  for (int i = threadIdx.x; i < cnt; i += 256){
    int d = (int)(b[i] & 0xffffffffu);
    atomicAdd(&hist[d - lo], 1);
  }
  __syncthreads();
  for (int i = threadIdx.x; i < m; i += 256) deg[lo + i] = hist[i];
}

// one block per slice: LDS cursors (init from offs) -> csr scatter, L2-local
__global__ __launch_bounds__(256) void k_fill3(const ull* __restrict__ bkt,
                                               const int* __restrict__ bcnt,
                                               const int* __restrict__ offs,
                                               int* __restrict__ csr,
                                               int cap, int SL, int n){
  __shared__ int cur[MAXSL];
  int s = blockIdx.x;
  int lo = s * SL;
  int m = n - lo; if (m > SL) m = SL; if (m < 0) m = 0;
  for (int i = threadIdx.x; i < m; i += 256) cur[i] = offs[lo + i];
  __syncthreads();
  int cnt = min(bcnt[s], cap);
  const ull* b = bkt + (size_t)s * cap;
  for (int i = threadIdx.x; i < cnt; i += 256){
    ull pk = b[i];
    int d  = (int)(pk & 0xffffffffu);
    int sr = (int)(pk >> 32);
    int p  = atomicAdd(&cur[d - lo], 1);
    csr[p] = sr;
  }
}

// ---------------- scans (+prep fused into scanC) ----------------

__global__ __launch_bounds__(256) void k_scanA(const int* __restrict__ deg,
                                               int* __restrict__ bsum, int n){
  __shared__ int sm[256];
  int b = blockIdx.x, t = threadIdx.x;
  int base = b * 1024 + t * 4;
  int s = 0;
  #pragma unroll
  for (int u = 0; u < 4; ++u){ int i = base + u; if (i < n) s += deg[i]; }
  sm[t] = s; __syncthreads();
  for (int off = 128; off > 0; off >>= 1){
    if (t < off) sm[t] += sm[t + off];
    __syncthreads();
  }
  if (t == 0) bsum[b] = sm[0];
}

__global__ void k_scanB(const int* __restrict__ bsum, int* __restrict__ bscan,
                        int* __restrict__ offs, int nb, int n){
  if (blockIdx.x == 0 && threadIdx.x == 0){
    int run = 0;
    for (int i = 0; i < nb; ++i){ bscan[i] = run; run += bsum[i]; }
    offs[n] = run;
  }
}

__global__ __launch_bounds__(256) void k_scanC(const int* __restrict__ deg,
                                               const int* __restrict__ bscan,
                                               int* __restrict__ offs,
                                               float* __restrict__ dis,
                                               float* __restrict__ invd, int n){
  __shared__ int sm[256];
  int b = blockIdx.x, t = threadIdx.x;
  int base = b * 1024 + t * 4;
  int v0 = (base + 0 < n) ? deg[base + 0] : 0;
  int v1 = (base + 1 < n) ? deg[base + 1] : 0;
  int v2 = (base + 2 < n) ? deg[base + 2] : 0;
  int v3 = (base + 3 < n) ? deg[base + 3] : 0;
  int ts = v0 + v1 + v2 + v3;
  sm[t] = ts; __syncthreads();
  #pragma unroll
  for (int off = 1; off < 256; off <<= 1){
    int add = (t >= off) ? sm[t - off] : 0;
    __syncthreads();
    sm[t] += add;
    __syncthreads();
  }
  int excl = sm[t] - ts;
  int run = bscan[b] + excl;
  if (base + 0 < n) offs[base + 0] = run; run += v0;
  if (base + 1 < n) offs[base + 1] = run; run += v1;
  if (base + 2 < n) offs[base + 2] = run; run += v2;
  if (base + 3 < n) offs[base + 3] = run; run += v3;
  #pragma unroll
  for (int u = 0; u < 4; ++u){
    int i = base + u;
    if (i < n){
      float d = (float)((u == 0) ? v0 : (u == 1) ? v1 : (u == 2) ? v2 : v3);
      dis[i]  = rsqrtf(d + 1.0f);       // GCN: deg includes self-loop
      invd[i] = 1.0f / fmaxf(d, 1.0f);  // SAGE mean divisor
    }
  }
}

// ---------------- fp32 -> premultiplied fp16, pass-major [4][n][16] --------

__global__ __launch_bounds__(256) void k_f2h(const float* __restrict__ in,
                                             const float* __restrict__ dis,
                                             ushort* __restrict__ out, int n){
  int i = blockIdx.x * 256 + threadIdx.x;
  if (i >= n * 4) return;
  int node = i >> 2, q = i & 3;
  float w = dis[node];
  const float4* xr = (const float4*)(in + (size_t)node * 64 + q * 16);
  float4 a = xr[0], b = xr[1], c = xr[2], d = xr[3];
  a.x*=w; a.y*=w; a.z*=w; a.w*=w;  b.x*=w; b.y*=w; b.z*=w; b.w*=w;
  c.x*=w; c.y*=w; c.z*=w; c.w*=w;  d.x*=w; d.y*=w; d.z*=w; d.w*=w;
  ushort* o = out + (size_t)q * n * 16 + (size_t)node * 16;
  *(ushort4*)(o + 0)  = pack_h4(a);
  *(ushort4*)(o + 4)  = pack_h4(b);
  *(ushort4*)(o + 8)  = pack_h4(c);
  *(ushort4*)(o + 12) = pack_h4(d);
}

// ---------------- Aggregation: 4-quarter, 2 nodes/wave ---------------------
// in/out pass-major [4][n][16]. Pass p = bid/nq (dispatch-order phase
// separation keeps the 3.2MB quarter table XCD-L2-resident). Per wave: 2
// nodes x 16 neighbor slots x 2 feature-halves; one vmem instr = 32 rows.
// MODE 0: GCN (hh premultiplied by dis): out = dis_i * (sum_j hh_j + hh_i)
// MODE 1: SAGE: out = (sum_j hh_j) / max(deg,1)

template<int MODE>
__global__ __launch_bounds__(256) void k_agg(const ushort* __restrict__ in,
                                             const int* __restrict__ offs,
                                             const int* __restrict__ csr,
                                             const float* __restrict__ dis,
                                             const float* __restrict__ invd,
                                             float* __restrict__ out,
                                             int n, int nq){
  int bid = blockIdx.x;
  int p  = bid / nq;
  int nb = bid - p * nq;
  int t = threadIdx.x;
  int lane = t & 63;
  int wv   = t >> 6;
  int half = lane >> 5;          // node within wave
  int g    = (lane >> 1) & 15;   // neighbor slot
  int h    = lane & 1;           // feature half (8 fp16)
  int node = nb * 8 + wv * 2 + half;
  bool valid = node < n;
  int nd = valid ? node : 0;
  const ushort* tbl = in + (size_t)p * n * 16;
  int s = valid ? offs[nd] : 0;
  int e = valid ? offs[nd + 1] : 0;

  float acc[8] = {0.f,0.f,0.f,0.f,0.f,0.f,0.f,0.f};
  #pragma unroll 2
  for (int k = s + g; k < e; k += 16){
    int j = csr[k];
    ushort8v v = *(const ushort8v*)(tbl + (size_t)j * 16 + h * 8);
    #pragma unroll
    for (int q = 0; q < 8; ++q)
      acc[q] += __half2float(__ushort_as_half(v[q]));
  }

  // reduce across the 16 neighbor slots (lane bits 1..4)
  #pragma unroll
  for (int q = 0; q < 8; ++q) acc[q] += __shfl_xor(acc[q], 2);
  #pragma unroll
  for (int q = 0; q < 8; ++q) acc[q] += __shfl_xor(acc[q], 4);
  #pragma unroll
  for (int q = 0; q < 8; ++q) acc[q] += __shfl_xor(acc[q], 8);
  #pragma unroll
  for (int q = 0; q < 8; ++q) acc[q] += __shfl_xor(acc[q], 16);

  if (valid && g == 0){
    float r[8];
    if (MODE == 0){
      float di = dis[nd];
      ushort8v self = *(const ushort8v*)(tbl + (size_t)nd * 16 + h * 8);
      #pragma unroll
      for (int q = 0; q < 8; ++q)
        r[q] = di * (acc[q] + __half2float(__ushort_as_half(self[q])));
    } else {
      float iv = invd[nd];
      #pragma unroll
      for (int q = 0; q < 8; ++q) r[q] = acc[q] * iv;
    }
    float* o = out + (size_t)p * n * 16 + (size_t)nd * 16 + h * 8;
    *(float4*)(o + 0) = make_float4(r[0], r[1], r[2], r[3]);
    *(float4*)(o + 4) = make_float4(r[4], r[5], r[6], r[7]);
  }
}

// ---------------- Dense 64x64 GEMM tiles ----------------
// A-operand comes from agg output in pass-major [4][n][16] (stage_A4);
// residual/B operands are normal [n][64] fp32 (stage_A).

__device__ __forceinline__ void stage_A(const float* __restrict__ A,
                                        float (*As)[68], int row0, int n, int t){
  #pragma unroll
  for (int u = 0; u < 4; ++u){
    int q = u * 256 + t;
    int r = q >> 4;
    int c = (q & 15) * 4;
    int gr = row0 + r;
    float4 v = make_float4(0.f, 0.f, 0.f, 0.f);
    if (gr < n) v = *(const float4*)(A + (size_t)gr * 64 + c);
    *(float4*)&As[r][c] = v;
  }
}

__device__ __forceinline__ void stage_A4(const float* __restrict__ A,
                                         float (*As)[68], int row0, int n, int t){
  #pragma unroll
  for (int u = 0; u < 4; ++u){
    int q = u * 256 + t;
    int r = q >> 4;
    int c4 = (q & 15) * 4;
    int p = c4 >> 4;
    int off = c4 & 15;
    int gr = row0 + r;
    float4 v = make_float4(0.f, 0.f, 0.f, 0.f);
    if (gr < n) v = *(const float4*)(A + (size_t)p * n * 16 + (size_t)gr * 16 + off);
    *(float4*)&As[r][c4] = v;
  }
}

__device__ __forceinline__ void stage_W(const float* __restrict__ W,
                                        float (*Ws)[64], int t){
  #pragma unroll
  for (int u = 0; u < 4; ++u){
    int q = u * 256 + t;
    int r = q >> 4;
    int c = (q & 15) * 4;
    *(float4*)&Ws[r][c] = *(const float4*)(W + r * 64 + c);
  }
}

__device__ __forceinline__ void tile_mm(const float (*As)[68], const float (*Ws)[64],
                                        float4 acc[4], int r0, int c0){
  #pragma unroll 2
  for (int k0 = 0; k0 < 64; k0 += 4){
    float4 a0 = *(const float4*)&As[r0+0][k0];
    float4 a1 = *(const float4*)&As[r0+1][k0];
    float4 a2 = *(const float4*)&As[r0+2][k0];
    float4 a3 = *(const float4*)&As[r0+3][k0];
    float4 w0 = *(const float4*)&Ws[k0+0][c0];
    float4 w1 = *(const float4*)&Ws[k0+1][c0];
    float4 w2 = *(const float4*)&Ws[k0+2][c0];
    float4 w3 = *(const float4*)&Ws[k0+3][c0];
    fma4(acc[0], a0.x, w0); fma4(acc[0], a0.y, w1); fma4(acc[0], a0.z, w2); fma4(acc[0], a0.w, w3);
    fma4(acc[1], a1.x, w0); fma4(acc[1], a1.y, w1); fma4(acc[1], a1.z, w2); fma4(acc[1], a1.w, w3);
    fma4(acc[2], a2.x, w0); fma4(acc[2], a2.y, w1); fma4(acc[2], a2.z, w2); fma4(acc[2], a2.w, w3);
    fma4(acc[3], a3.x, w0); fma4(acc[3], a3.y, w1); fma4(acc[3], a3.z, w2); fma4(acc[3], a3.w, w3);
  }
}

__device__ __forceinline__ void mirror_h(ushort* outh, int gr, int c0, int n, float4 v){
  *(ushort4*)(outh + (size_t)(c0 >> 4) * n * 16 + (size_t)gr * 16 + (c0 & 15)) = pack_h4(v);
}

// out = act(A4 @ W + bias)  [+ pass-major fp16 mirror if outh]
template<bool RELU>
__global__ __launch_bounds__(256, 2) void k_gemm1(const float* __restrict__ A,
                                                  const float* __restrict__ W,
                                                  const float* __restrict__ bias,
                                                  float* __restrict__ out,
                                                  ushort* __restrict__ outh, int n){
  __shared__ __align__(16) float As[64][68];
  __shared__ __align__(16) float Ws[64][64];
  int t = threadIdx.x;
  int row0 = blockIdx.x * 64;
  stage_W(W, Ws, t);
  stage_A4(A, As, row0, n, t);
  __syncthreads();
  int r0 = (t >> 4) * 4, c0 = (t & 15) * 4;
  float4 b4 = *(const float4*)(bias + c0);
  float4 acc[4] = {b4, b4, b4, b4};
  tile_mm(As, Ws, acc, r0, c0);
  #pragma unroll
  for (int i = 0; i < 4; ++i){
    int gr = row0 + r0 + i;
    if (gr < n){
      float4 v = acc[i];
      if (RELU){
        v.x = fmaxf(v.x, 0.f); v.y = fmaxf(v.y, 0.f);
        v.z = fmaxf(v.z, 0.f); v.w = fmaxf(v.w, 0.f);
      }
      *(float4*)(out + (size_t)gr * 64 + c0) = v;
      if (outh) mirror_h(outh, gr, c0, n, v);
    }
  }
}

// out = act(A4 @ W1 + B @ W2 + bias + B)   (SAGE layer with residual)
template<bool RELU>
__global__ __launch_bounds__(256, 2) void k_gemm_dual(const float* __restrict__ A,
                                                      const float* __restrict__ B,
                                                      const float* __restrict__ W1,
                                                      const float* __restrict__ W2,
                                                      const float* __restrict__ bias,
                                                      float* __restrict__ out,
                                                      ushort* __restrict__ outh, int n){
  __shared__ __align__(16) float As[64][68];
  __shared__ __align__(16) float Ws1[64][64];
  __shared__ __align__(16) float Ws2[64][64];
  int t = threadIdx.x;
  int row0 = blockIdx.x * 64;
  stage_W(W1, Ws1, t);
  stage_W(W2, Ws2, t);
  stage_A4(A, As, row0, n, t);
  __syncthreads();
  int r0 = (t >> 4) * 4, c0 = (t & 15) * 4;
  float4 b4 = *(const float4*)(bias + c0);
  float4 acc[4] = {b4, b4, b4, b4};
  tile_mm(As, Ws1, acc, r0, c0);
  __syncthreads();
  stage_A(B, As, row0, n, t);
  __syncthreads();
  tile_mm(As, Ws2, acc, r0, c0);
  #pragma unroll
  for (int i = 0; i < 4; ++i){
    float4 res = *(const float4*)&As[r0 + i][c0];
    acc[i].x += res.x; acc[i].y += res.y; acc[i].z += res.z; acc[i].w += res.w;
    if (RELU){
      acc[i].x = fmaxf(acc[i].x, 0.f); acc[i].y = fmaxf(acc[i].y, 0.f);
      acc[i].z = fmaxf(acc[i].z, 0.f); acc[i].w = fmaxf(acc[i].w, 0.f);
    }
    int gr = row0 + r0 + i;
    if (gr < n){
      *(float4*)(out + (size_t)gr * 64 + c0) = acc[i];
      if (outh) mirror_h(outh, gr, c0, n, acc[i]);
    }
  }
}

// hh = fp16(dis * relu((A4@W1 + B@W2 + b12 + B) @ W3 + b3))  (pass-major only)
__global__ __launch_bounds__(256, 2) void k_gemm_tri(const float* __restrict__ A,
                                                     const float* __restrict__ B,
                                                     const float* __restrict__ W1,
                                                     const float* __restrict__ W2,
                                                     const float* __restrict__ b12,
                                                     const float* __restrict__ W3,
                                                     const float* __restrict__ b3,
                                                     const float* __restrict__ dis,
                                                     ushort* __restrict__ outh, int n){
  __shared__ __align__(16) float As[64][68];
  __shared__ __align__(16) float Ws1[64][64];
  __shared__ __align__(16) float Ws2[64][64];
  int t = threadIdx.x;
  int row0 = blockIdx.x * 64;
  stage_W(W1, Ws1, t);
  stage_W(W2, Ws2, t);
  stage_A4(A, As, row0, n, t);
  __syncthreads();
  int r0 = (t >> 4) * 4, c0 = (t & 15) * 4;
  float4 b4 = *(const float4*)(b12 + c0);
  float4 acc[4] = {b4, b4, b4, b4};
  tile_mm(As, Ws1, acc, r0, c0);
  __syncthreads();
  stage_A(B, As, row0, n, t);
  __syncthreads();
  tile_mm(As, Ws2, acc, r0, c0);
  #pragma unroll
  for (int i = 0; i < 4; ++i){
    float4 res = *(const float4*)&As[r0 + i][c0];
    acc[i].x += res.x; acc[i].y += res.y; acc[i].z += res.z; acc[i].w += res.w;
  }
  __syncthreads();
  #pragma unroll
  for (int i = 0; i < 4; ++i) *(float4*)&As[r0 + i][c0] = acc[i];
  stage_W(W3, Ws1, t);
  __syncthreads();
  float4 bb = *(const float4*)(b3 + c0);
  float4 acc2[4] = {bb, bb, bb, bb};
  tile_mm(As, Ws1, acc2, r0, c0);
  #pragma unroll
  for (int i = 0; i < 4; ++i){
    int gr = row0 + r0 + i;
    if (gr < n){
      float4 v = acc2[i];
      v.x = fmaxf(v.x, 0.f); v.y = fmaxf(v.y, 0.f);
      v.z = fmaxf(v.z, 0.f); v.w = fmaxf(v.w, 0.f);
      float w = dis[gr];
      v.x *= w; v.y *= w; v.z *= w; v.w *= w;
      mirror_h(outh, gr, c0, n, v);
    }
  }
}

// ---------------------------------------------------------------------------

extern "C" void kernel_launch(void* const* d_in, const int* in_sizes, int n_in,
                              void* d_out, int out_size, void* d_ws, size_t ws_size,
                              hipStream_t stream){
  const float* x        = (const float*)d_in[0];
  const int*   ei       = (const int*)  d_in[1];
  const float* gcn1_w   = (const float*)d_in[2];
  const float* gcn1_b   = (const float*)d_in[3];
  const float* sage1_lw = (const float*)d_in[4];
  const float* sage1_lb = (const float*)d_in[5];
  const float* sage1_rw = (const float*)d_in[6];
  const float* sage2_lw = (const float*)d_in[7];
  const float* sage2_lb = (const float*)d_in[8];
  const float* sage2_rw = (const float*)d_in[9];
  const float* lin_w    = (const float*)d_in[10];
  const float* lin_b    = (const float*)d_in[11];
  const float* gcn2_w   = (const float*)d_in[12];
  const float* gcn2_b   = (const float*)d_in[13];
  float* out = (float*)d_out;

  const int n = in_sizes[0] / 64;
  const int E = in_sizes[1] / 2;
  const int* src = ei;
  const int* dst = ei + E;
  const int SL  = (n + NSL - 1) / NSL;
  const int cap = E / 4;

  uintptr_t p = (uintptr_t)d_ws;
  auto alloc = [&](size_t b) -> void* {
    p = (p + 255) & ~(uintptr_t)255;
    void* r = (void*)p; p += b; return r;
  };
  float*  bufA = (float*)alloc((size_t)n * 64 * 4);   // agg out, pass-major [4][n][16]
  float*  bufB = (float*)alloc((size_t)n * 64 * 4);   // h2 fp32 [n][64]
  ushort* hh   = (ushort*)alloc((size_t)n * 64 * 2);  // fp16 mirror, pass-major [4][n][16]
  int*    deg  = (int*)  alloc((size_t)(n + 8) * 4);
  int*    bcnt = deg + n;
  int*    offs = (int*)  alloc((size_t)(n + 1) * 4);
  const int NB = (n + 1023) / 1024;
  int*    bsum  = (int*) alloc((size_t)NB * 4);
  int*    bscan = (int*) alloc((size_t)NB * 4);
  int*    csr   = (int*) alloc((size_t)E * 4);
  float*  dis   = (float*)alloc((size_t)n * 4);
  float*  invd  = (float*)alloc((size_t)n * 4);
  ull*    bkt   = (ull*)bufA;                         // 20MB, dead during CSR build

  hipMemsetAsync(bcnt, 0, 8 * 4, stream);

  const int nq = (n + 7) / 8;          // blocks per agg pass (8 nodes/block)
  const int gAgg = 4 * nq;             // 4 quarter-passes in one launch
  const int gG = (n + 63) / 64;
  const int gC = (n * 4 + 255) / 256;

  // CSR build: bucket scatter -> slice-LDS deg -> scan(+prep) -> slice-LDS fill
  k_bucket<<<BKT_BLOCKS, 256, 0, stream>>>(src, dst, bkt, bcnt, E, SL, cap);
  k_deg3  <<<NSL, 256, 0, stream>>>(bkt, bcnt, deg, cap, SL, n);
  k_scanA <<<NB, 256, 0, stream>>>(deg, bsum, n);
  k_scanB <<<1, 1, 0, stream>>>(bsum, bscan, offs, NB, n);
  k_scanC <<<NB, 256, 0, stream>>>(deg, bscan, offs, dis, invd, n);
  k_fill3 <<<NSL, 256, 0, stream>>>(bkt, bcnt, offs, csr, cap, SL, n);

  // Layer 1: h1 = relu(GCNagg(x) @ gcn1_w + b)           -> d_out (+hh)
  k_f2h<<<gC, 256, 0, stream>>>(x, dis, hh, n);            // hh = dis*x (pass-major)
  k_agg<0><<<gAgg, 256, 0, stream>>>(hh, offs, csr, dis, invd, bufA, n, nq);
  k_gemm1<true><<<gG, 256, 0, stream>>>(bufA, gcn1_w, gcn1_b, out, hh, n);

  // Layer 2: h2 = relu(mean(h1)@Wl + bl + h1@Wr + h1)    -> bufB (+hh)
  k_agg<1><<<gAgg, 256, 0, stream>>>(hh, offs, csr, dis, invd, bufA, n, nq);
  k_gemm_dual<true><<<gG, 256, 0, stream>>>(bufA, out, sage1_lw, sage1_rw, sage1_lb, bufB, hh, n);

  // Layer 3 (fused): hh = dis*relu((mean(h2)@Wl2+bl2+h2@Wr2+h2)@lin_w+lin_b)
  k_agg<1><<<gAgg, 256, 0, stream>>>(hh, offs, csr, dis, invd, bufA, n, nq);
  k_gemm_tri<<<gG, 256, 0, stream>>>(bufA, bufB, sage2_lw, sage2_rw, sage2_lb,
                                     lin_w, lin_b, dis, hh, n);

  // Layer 4: out = GCNagg(h4) @ gcn2_w + gcn2_b          -> d_out
  k_agg<0><<<gAgg, 256, 0, stream>>>(hh, offs, csr, dis, invd, bufA, n, nq);
  k_gemm1<false><<<gG, 256, 0, stream>>>(bufA, gcn2_w, gcn2_b, out, (ushort*)nullptr, n);
}

// Round 11
// 668.217 us; speedup vs baseline: 1.2616x; 1.2616x over previous
//
#include <hip/hip_runtime.h>
#include <hip/hip_fp16.h>
#include <stdint.h>

// ---------------------------------------------------------------------------
// GNN forward: GCN -> SAGE(+res) -> SAGE(+res) -> lin -> GCN
// R2: bounded unroll fixed GEMM spill.  R3/R4: wide gather + fp16 mirror.
// R5: bucket scatter.  R6: work-steal regressed.  R7: 8x8 gather + fused deg.
// R8: wave-agg ballot bucket (61us), fill2@2048 (45us). Total 495.
// R9: slice-LDS deg/fill = 8 blocks = 0.35% occupancy -> 218us each. REVERTED.
// R10: NT-stream agg (theory: keep 3.2MB quarter table XCD-L2-resident by not
//      polluting L2 with csr + output streams). Compile error: nontemporal
//      builtin needs native vector type, not HIP_vector_type.
// R11: fix = ext_vector_type(4) float alias for the NT stores. Same theory.
// ---------------------------------------------------------------------------

typedef unsigned long long ull;
typedef unsigned short ushort8v __attribute__((ext_vector_type(8)));
typedef float float4v __attribute__((ext_vector_type(4)));

#define NSL 8
#define BKT_BLOCKS 1024
#define FILL_BLOCKS 2048

__device__ __forceinline__ void fma4(float4& a, float s, const float4& w){
  a.x = fmaf(s, w.x, a.x);
  a.y = fmaf(s, w.y, a.y);
  a.z = fmaf(s, w.z, a.z);
  a.w = fmaf(s, w.w, a.w);
}

__device__ __forceinline__ ushort4 pack_h4(float4 v){
  ushort4 u;
  u.x = __half_as_ushort(__float2half(v.x));
  u.y = __half_as_ushort(__float2half(v.y));
  u.z = __half_as_ushort(__float2half(v.z));
  u.w = __half_as_ushort(__float2half(v.w));
  return u;
}

__device__ __forceinline__ ull slice_group(bool act, int s){
  ull bm = __ballot(act);
  ull m0 = __ballot(s & 1);
  ull m1 = __ballot(s & 2);
  ull m2 = __ballot(s & 4);
  ull g = bm;
  g &= (s & 1) ? m0 : ~m0;
  g &= (s & 2) ? m1 : ~m1;
  g &= (s & 4) ? m2 : ~m2;
  return g;
}

// ---------------- CSR build (R8 proven form) ----------------

__global__ __launch_bounds__(256) void k_bucket(const int* __restrict__ src,
                                                const int* __restrict__ dst,
                                                ull* __restrict__ bkt,
                                                int* __restrict__ bcnt,
                                                int* __restrict__ deg,
                                                int E, int SL, int cap){
  __shared__ int hist[NSL];
  __shared__ int cur[NSL];
  int t = threadIdx.x;
  int lane = t & 63;
  int chunk = (E + BKT_BLOCKS - 1) / BKT_BLOCKS;
  int e0 = blockIdx.x * chunk;
  int e1 = min(E, e0 + chunk);
  if (t < NSL) hist[t] = 0;
  __syncthreads();
  // pass 1: deg atomics (fire-and-forget) + wave-aggregated slice histogram
  for (int base = e0; base < e1; base += 256){
    int e = base + t;
    bool act = e < e1;
    int d = 0, s = 0;
    if (act){
      d = dst[e];
      s = d / SL;
      atomicAdd(&deg[d], 1);
    }
    ull g = slice_group(act, s);
    if (act && lane == (__ffsll((long long)g) - 1))
      atomicAdd(&hist[s], __popcll(g));
  }
  __syncthreads();
  if (t < NSL){
    int h = hist[t];
    cur[t] = h ? atomicAdd(&bcnt[t], h) : 0;
  }
  __syncthreads();
  // pass 2: wave-aggregated rank + scatter (chunk re-read is L2-hot)
  for (int base = e0; base < e1; base += 256){
    int e = base + t;
    bool act = e < e1;
    int s = 0; ull pk = 0;
    if (act){
      int d = dst[e];
      s = d / SL;
      pk = ((ull)(unsigned)src[e] << 32) | (unsigned)d;
    }
    ull g = slice_group(act, s);
    int leader = __ffsll((long long)g) - 1;
    int rank = __popcll(g & ((1ull << lane) - 1));
    int bs = 0;
    if (act && lane == leader) bs = atomicAdd(&cur[s], __popcll(g));
    bs = __shfl(bs, leader);
    if (act){
      int pos = bs + rank;
      if (pos < cap) bkt[(size_t)s * cap + pos] = pk;
    }
  }
}

__global__ __launch_bounds__(256) void k_fill2(const ull* __restrict__ bkt,
                                               const int* __restrict__ bcnt,
                                               const int* __restrict__ offs,
                                               int* __restrict__ deg,
                                               int* __restrict__ csr, int cap){
  int s = blockIdx.x & 7;
  int q = blockIdx.x >> 3;
  int cnt = min(bcnt[s], cap);
  const ull* b = bkt + (size_t)s * cap;
  for (int i = q * 256 + threadIdx.x; i < cnt; i += (FILL_BLOCKS / 8) * 256){
    ull pk = b[i];
    int d  = (int)(pk & 0xffffffffu);
    int sr = (int)(pk >> 32);
    int p  = offs[d] + atomicSub(&deg[d], 1) - 1;
    csr[p] = sr;
  }
}

// ---------------- scans (+prep fused into scanC) ----------------

__global__ __launch_bounds__(256) void k_scanA(const int* __restrict__ deg,
                                               int* __restrict__ bsum, int n){
  __shared__ int sm[256];
  int b = blockIdx.x, t = threadIdx.x;
  int base = b * 1024 + t * 4;
  int s = 0;
  #pragma unroll
  for (int u = 0; u < 4; ++u){ int i = base + u; if (i < n) s += deg[i]; }
  sm[t] = s; __syncthreads();
  for (int off = 128; off > 0; off >>= 1){
    if (t < off) sm[t] += sm[t + off];
    __syncthreads();
  }
  if (t == 0) bsum[b] = sm[0];
}

__global__ void k_scanB(const int* __restrict__ bsum, int* __restrict__ bscan,
                        int* __restrict__ offs, int nb, int n){
  if (blockIdx.x == 0 && threadIdx.x == 0){
    int run = 0;
    for (int i = 0; i < nb; ++i){ bscan[i] = run; run += bsum[i]; }
    offs[n] = run;
  }
}

__global__ __launch_bounds__(256) void k_scanC(const int* __restrict__ deg,
                                               const int* __restrict__ bscan,
                                               int* __restrict__ offs,
                                               float* __restrict__ dis,
                                               float* __restrict__ invd, int n){
  __shared__ int sm[256];
  int b = blockIdx.x, t = threadIdx.x;
  int base = b * 1024 + t * 4;
  int v0 = (base + 0 < n) ? deg[base + 0] : 0;
  int v1 = (base + 1 < n) ? deg[base + 1] : 0;
  int v2 = (base + 2 < n) ? deg[base + 2] : 0;
  int v3 = (base + 3 < n) ? deg[base + 3] : 0;
  int ts = v0 + v1 + v2 + v3;
  sm[t] = ts; __syncthreads();
  #pragma unroll
  for (int off = 1; off < 256; off <<= 1){
    int add = (t >= off) ? sm[t - off] : 0;
    __syncthreads();
    sm[t] += add;
    __syncthreads();
  }
  int excl = sm[t] - ts;
  int run = bscan[b] + excl;
  if (base + 0 < n) offs[base + 0] = run; run += v0;
  if (base + 1 < n) offs[base + 1] = run; run += v1;
  if (base + 2 < n) offs[base + 2] = run; run += v2;
  if (base + 3 < n) offs[base + 3] = run; run += v3;
  #pragma unroll
  for (int u = 0; u < 4; ++u){
    int i = base + u;
    if (i < n){
      float d = (float)((u == 0) ? v0 : (u == 1) ? v1 : (u == 2) ? v2 : v3);
      dis[i]  = rsqrtf(d + 1.0f);       // GCN: deg includes self-loop
      invd[i] = 1.0f / fmaxf(d, 1.0f);  // SAGE mean divisor
    }
  }
}

// ---------------- fp32 -> premultiplied fp16, pass-major [4][n][16] --------

__global__ __launch_bounds__(256) void k_f2h(const float* __restrict__ in,
                                             const float* __restrict__ dis,
                                             ushort* __restrict__ out, int n){
  int i = blockIdx.x * 256 + threadIdx.x;
  if (i >= n * 4) return;
  int node = i >> 2, q = i & 3;
  float w = dis[node];
  const float4* xr = (const float4*)(in + (size_t)node * 64 + q * 16);
  float4 a = xr[0], b = xr[1], c = xr[2], d = xr[3];
  a.x*=w; a.y*=w; a.z*=w; a.w*=w;  b.x*=w; b.y*=w; b.z*=w; b.w*=w;
  c.x*=w; c.y*=w; c.z*=w; c.w*=w;  d.x*=w; d.y*=w; d.z*=w; d.w*=w;
  ushort* o = out + (size_t)q * n * 16 + (size_t)node * 16;
  *(ushort4*)(o + 0)  = pack_h4(a);
  *(ushort4*)(o + 4)  = pack_h4(b);
  *(ushort4*)(o + 8)  = pack_h4(c);
  *(ushort4*)(o + 12) = pack_h4(d);
}

// ---------------- Aggregation: 4-quarter, 2 nodes/wave, NT streams ---------
// in/out pass-major [4][n][16]; pass p = bid/nq. csr loads and output stores
// are NON-TEMPORAL so the 3.2MB quarter table stays XCD-L2-resident.
// MODE 0: GCN (hh premultiplied by dis): out = dis_i * (sum_j hh_j + hh_i)
// MODE 1: SAGE: out = (sum_j hh_j) / max(deg,1)

template<int MODE>
__global__ __launch_bounds__(256) void k_agg(const ushort* __restrict__ in,
                                             const int* __restrict__ offs,
                                             const int* __restrict__ csr,
                                             const float* __restrict__ dis,
                                             const float* __restrict__ invd,
                                             float* __restrict__ out,
                                             int n, int nq){
  int bid = blockIdx.x;
  int p  = bid / nq;
  int nb = bid - p * nq;
  int t = threadIdx.x;
  int lane = t & 63;
  int wv   = t >> 6;
  int half = lane >> 5;          // node within wave
  int g    = (lane >> 1) & 15;   // neighbor slot
  int h    = lane & 1;           // feature half (8 fp16)
  int node = nb * 8 + wv * 2 + half;
  bool valid = node < n;
  int nd = valid ? node : 0;
  const ushort* tbl = in + (size_t)p * n * 16;
  int s = valid ? offs[nd] : 0;
  int e = valid ? offs[nd + 1] : 0;

  float acc[8] = {0.f,0.f,0.f,0.f,0.f,0.f,0.f,0.f};
  #pragma unroll 2
  for (int k = s + g; k < e; k += 16){
    int j = __builtin_nontemporal_load(csr + k);
    ushort8v v = *(const ushort8v*)(tbl + (size_t)j * 16 + h * 8);
    #pragma unroll
    for (int q = 0; q < 8; ++q)
      acc[q] += __half2float(__ushort_as_half(v[q]));
  }

  // reduce across the 16 neighbor slots (lane bits 1..4)
  #pragma unroll
  for (int q = 0; q < 8; ++q) acc[q] += __shfl_xor(acc[q], 2);
  #pragma unroll
  for (int q = 0; q < 8; ++q) acc[q] += __shfl_xor(acc[q], 4);
  #pragma unroll
  for (int q = 0; q < 8; ++q) acc[q] += __shfl_xor(acc[q], 8);
  #pragma unroll
  for (int q = 0; q < 8; ++q) acc[q] += __shfl_xor(acc[q], 16);

  if (valid && g == 0){
    float r[8];
    if (MODE == 0){
      float di = dis[nd];
      ushort8v self = *(const ushort8v*)(tbl + (size_t)nd * 16 + h * 8);
      #pragma unroll
      for (int q = 0; q < 8; ++q)
        r[q] = di * (acc[q] + __half2float(__ushort_as_half(self[q])));
    } else {
      float iv = invd[nd];
      #pragma unroll
      for (int q = 0; q < 8; ++q) r[q] = acc[q] * iv;
    }
    float4v* o4 = (float4v*)(out + (size_t)p * n * 16 + (size_t)nd * 16 + h * 8);
    float4v w0 = {r[0], r[1], r[2], r[3]};
    float4v w1 = {r[4], r[5], r[6], r[7]};
    __builtin_nontemporal_store(w0, o4);
    __builtin_nontemporal_store(w1, o4 + 1);
  }
}

// ---------------- Dense 64x64 GEMM tiles ----------------

__device__ __forceinline__ void stage_A(const float* __restrict__ A,
                                        float (*As)[68], int row0, int n, int t){
  #pragma unroll
  for (int u = 0; u < 4; ++u){
    int q = u * 256 + t;
    int r = q >> 4;
    int c = (q & 15) * 4;
    int gr = row0 + r;
    float4 v = make_float4(0.f, 0.f, 0.f, 0.f);
    if (gr < n) v = *(const float4*)(A + (size_t)gr * 64 + c);
    *(float4*)&As[r][c] = v;
  }
}

__device__ __forceinline__ void stage_A4(const float* __restrict__ A,
                                         float (*As)[68], int row0, int n, int t){
  #pragma unroll
  for (int u = 0; u < 4; ++u){
    int q = u * 256 + t;
    int r = q >> 4;
    int c4 = (q & 15) * 4;
    int p = c4 >> 4;
    int off = c4 & 15;
    int gr = row0 + r;
    float4 v = make_float4(0.f, 0.f, 0.f, 0.f);
    if (gr < n) v = *(const float4*)(A + (size_t)p * n * 16 + (size_t)gr * 16 + off);
    *(float4*)&As[r][c4] = v;
  }
}

__device__ __forceinline__ void stage_W(const float* __restrict__ W,
                                        float (*Ws)[64], int t){
  #pragma unroll
  for (int u = 0; u < 4; ++u){
    int q = u * 256 + t;
    int r = q >> 4;
    int c = (q & 15) * 4;
    *(float4*)&Ws[r][c] = *(const float4*)(W + r * 64 + c);
  }
}

__device__ __forceinline__ void tile_mm(const float (*As)[68], const float (*Ws)[64],
                                        float4 acc[4], int r0, int c0){
  #pragma unroll 2
  for (int k0 = 0; k0 < 64; k0 += 4){
    float4 a0 = *(const float4*)&As[r0+0][k0];
    float4 a1 = *(const float4*)&As[r0+1][k0];
    float4 a2 = *(const float4*)&As[r0+2][k0];
    float4 a3 = *(const float4*)&As[r0+3][k0];
    float4 w0 = *(const float4*)&Ws[k0+0][c0];
    float4 w1 = *(const float4*)&Ws[k0+1][c0];
    float4 w2 = *(const float4*)&Ws[k0+2][c0];
    float4 w3 = *(const float4*)&Ws[k0+3][c0];
    fma4(acc[0], a0.x, w0); fma4(acc[0], a0.y, w1); fma4(acc[0], a0.z, w2); fma4(acc[0], a0.w, w3);
    fma4(acc[1], a1.x, w0); fma4(acc[1], a1.y, w1); fma4(acc[1], a1.z, w2); fma4(acc[1], a1.w, w3);
    fma4(acc[2], a2.x, w0); fma4(acc[2], a2.y, w1); fma4(acc[2], a2.z, w2); fma4(acc[2], a2.w, w3);
    fma4(acc[3], a3.x, w0); fma4(acc[3], a3.y, w1); fma4(acc[3], a3.z, w2); fma4(acc[3], a3.w, w3);
  }
}

__device__ __forceinline__ void mirror_h(ushort* outh, int gr, int c0, int n, float4 v){
  *(ushort4*)(outh + (size_t)(c0 >> 4) * n * 16 + (size_t)gr * 16 + (c0 & 15)) = pack_h4(v);
}

// out = act(A4 @ W + bias)  [+ pass-major fp16 mirror if outh]
template<bool RELU>
__global__ __launch_bounds__(256, 2) void k_gemm1(const float* __restrict__ A,
                                                  const float* __restrict__ W,
                                                  const float* __restrict__ bias,
                                                  float* __restrict__ out,
                                                  ushort* __restrict__ outh, int n){
  __shared__ __align__(16) float As[64][68];
  __shared__ __align__(16) float Ws[64][64];
  int t = threadIdx.x;
  int row0 = blockIdx.x * 64;
  stage_W(W, Ws, t);
  stage_A4(A, As, row0, n, t);
  __syncthreads();
  int r0 = (t >> 4) * 4, c0 = (t & 15) * 4;
  float4 b4 = *(const float4*)(bias + c0);
  float4 acc[4] = {b4, b4, b4, b4};
  tile_mm(As, Ws, acc, r0, c0);
  #pragma unroll
  for (int i = 0; i < 4; ++i){
    int gr = row0 + r0 + i;
    if (gr < n){
      float4 v = acc[i];
      if (RELU){
        v.x = fmaxf(v.x, 0.f); v.y = fmaxf(v.y, 0.f);
        v.z = fmaxf(v.z, 0.f); v.w = fmaxf(v.w, 0.f);
      }
      *(float4*)(out + (size_t)gr * 64 + c0) = v;
      if (outh) mirror_h(outh, gr, c0, n, v);
    }
  }
}

// out = act(A4 @ W1 + B @ W2 + bias + B)   (SAGE layer with residual)
template<bool RELU>
__global__ __launch_bounds__(256, 2) void k_gemm_dual(const float* __restrict__ A,
                                                      const float* __restrict__ B,
                                                      const float* __restrict__ W1,
                                                      const float* __restrict__ W2,
                                                      const float* __restrict__ bias,
                                                      float* __restrict__ out,
                                                      ushort* __restrict__ outh, int n){
  __shared__ __align__(16) float As[64][68];
  __shared__ __align__(16) float Ws1[64][64];
  __shared__ __align__(16) float Ws2[64][64];
  int t = threadIdx.x;
  int row0 = blockIdx.x * 64;
  stage_W(W1, Ws1, t);
  stage_W(W2, Ws2, t);
  stage_A4(A, As, row0, n, t);
  __syncthreads();
  int r0 = (t >> 4) * 4, c0 = (t & 15) * 4;
  float4 b4 = *(const float4*)(bias + c0);
  float4 acc[4] = {b4, b4, b4, b4};
  tile_mm(As, Ws1, acc, r0, c0);
  __syncthreads();
  stage_A(B, As, row0, n, t);
  __syncthreads();
  tile_mm(As, Ws2, acc, r0, c0);
  #pragma unroll
  for (int i = 0; i < 4; ++i){
    float4 res = *(const float4*)&As[r0 + i][c0];
    acc[i].x += res.x; acc[i].y += res.y; acc[i].z += res.z; acc[i].w += res.w;
    if (RELU){
      acc[i].x = fmaxf(acc[i].x, 0.f); acc[i].y = fmaxf(acc[i].y, 0.f);
      acc[i].z = fmaxf(acc[i].z, 0.f); acc[i].w = fmaxf(acc[i].w, 0.f);
    }
    int gr = row0 + r0 + i;
    if (gr < n){
      *(float4*)(out + (size_t)gr * 64 + c0) = acc[i];
      if (outh) mirror_h(outh, gr, c0, n, acc[i]);
    }
  }
}

// hh = fp16(dis * relu((A4@W1 + B@W2 + b12 + B) @ W3 + b3))  (pass-major only)
__global__ __launch_bounds__(256, 2) void k_gemm_tri(const float* __restrict__ A,
                                                     const float* __restrict__ B,
                                                     const float* __restrict__ W1,
                                                     const float* __restrict__ W2,
                                                     const float* __restrict__ b12,
                                                     const float* __restrict__ W3,
                                                     const float* __restrict__ b3,
                                                     const float* __restrict__ dis,
                                                     ushort* __restrict__ outh, int n){
  __shared__ __align__(16) float As[64][68];
  __shared__ __align__(16) float Ws1[64][64];
  __shared__ __align__(16) float Ws2[64][64];
  int t = threadIdx.x;
  int row0 = blockIdx.x * 64;
  stage_W(W1, Ws1, t);
  stage_W(W2, Ws2, t);
  stage_A4(A, As, row0, n, t);
  __syncthreads();
  int r0 = (t >> 4) * 4, c0 = (t & 15) * 4;
  float4 b4 = *(const float4*)(b12 + c0);
  float4 acc[4] = {b4, b4, b4, b4};
  tile_mm(As, Ws1, acc, r0, c0);
  __syncthreads();
  stage_A(B, As, row0, n, t);
  __syncthreads();
  tile_mm(As, Ws2, acc, r0, c0);
  #pragma unroll
  for (int i = 0; i < 4; ++i){
    float4 res = *(const float4*)&As[r0 + i][c0];
    acc[i].x += res.x; acc[i].y += res.y; acc[i].z += res.z; acc[i].w += res.w;
  }
  __syncthreads();
  #pragma unroll
  for (int i = 0; i < 4; ++i) *(float4*)&As[r0 + i][c0] = acc[i];
  stage_W(W3, Ws1, t);
  __syncthreads();
  float4 bb = *(const float4*)(b3 + c0);
  float4 acc2[4] = {bb, bb, bb, bb};
  tile_mm(As, Ws1, acc2, r0, c0);
  #pragma unroll
  for (int i = 0; i < 4; ++i){
    int gr = row0 + r0 + i;
    if (gr < n){
      float4 v = acc2[i];
      v.x = fmaxf(v.x, 0.f); v.y = fmaxf(v.y, 0.f);
      v.z = fmaxf(v.z, 0.f); v.w = fmaxf(v.w, 0.f);
      float w = dis[gr];
      v.x *= w; v.y *= w; v.z *= w; v.w *= w;
      mirror_h(outh, gr, c0, n, v);
    }
  }
}

// ---------------------------------------------------------------------------

extern "C" void kernel_launch(void* const* d_in, const int* in_sizes, int n_in,
                              void* d_out, int out_size, void* d_ws, size_t ws_size,
                              hipStream_t stream){
  const float* x        = (const float*)d_in[0];
  const int*   ei       = (const int*)  d_in[1];
  const float* gcn1_w   = (const float*)d_in[2];
  const float* gcn1_b   = (const float*)d_in[3];
  const float* sage1_lw = (const float*)d_in[4];
  const float* sage1_lb = (const float*)d_in[5];
  const float* sage1_rw = (const float*)d_in[6];
  const float* sage2_lw = (const float*)d_in[7];
  const float* sage2_lb = (const float*)d_in[8];
  const float* sage2_rw = (const float*)d_in[9];
  const float* lin_w    = (const float*)d_in[10];
  const float* lin_b    = (const float*)d_in[11];
  const float* gcn2_w   = (const float*)d_in[12];
  const float* gcn2_b   = (const float*)d_in[13];
  float* out = (float*)d_out;

  const int n = in_sizes[0] / 64;
  const int E = in_sizes[1] / 2;
  const int* src = ei;
  const int* dst = ei + E;
  const int SL  = (n + NSL - 1) / NSL;
  const int cap = E / 4;

  uintptr_t p = (uintptr_t)d_ws;
  auto alloc = [&](size_t b) -> void* {
    p = (p + 255) & ~(uintptr_t)255;
    void* r = (void*)p; p += b; return r;
  };
  float*  bufA = (float*)alloc((size_t)n * 64 * 4);   // agg out, pass-major [4][n][16]
  float*  bufB = (float*)alloc((size_t)n * 64 * 4);   // h2 fp32 [n][64]
  ushort* hh   = (ushort*)alloc((size_t)n * 64 * 2);  // fp16 mirror, pass-major [4][n][16]
  int*    deg  = (int*)  alloc((size_t)(n + 8) * 4);
  int*    bcnt = deg + n;
  int*    offs = (int*)  alloc((size_t)(n + 1) * 4);
  const int NB = (n + 1023) / 1024;
  int*    bsum  = (int*) alloc((size_t)NB * 4);
  int*    bscan = (int*) alloc((size_t)NB * 4);
  int*    csr   = (int*) alloc((size_t)E * 4);
  float*  dis   = (float*)alloc((size_t)n * 4);
  float*  invd  = (float*)alloc((size_t)n * 4);
  ull*    bkt   = (ull*)bufA;                         // 20MB, dead during CSR build

  hipMemsetAsync(deg, 0, (size_t)(n + 8) * 4, stream);

  const int nq = (n + 7) / 8;          // blocks per agg pass (8 nodes/block)
  const int gAgg = 4 * nq;             // 4 quarter-passes in one launch
  const int gG = (n + 63) / 64;
  const int gC = (n * 4 + 255) / 256;

  // CSR build: bucket scatter(+deg) -> scan(+prep) -> slice-strided fill
  k_bucket<<<BKT_BLOCKS, 256, 0, stream>>>(src, dst, bkt, bcnt, deg, E, SL, cap);
  k_scanA <<<NB, 256, 0, stream>>>(deg, bsum, n);
  k_scanB <<<1, 1, 0, stream>>>(bsum, bscan, offs, NB, n);
  k_scanC <<<NB, 256, 0, stream>>>(deg, bscan, offs, dis, invd, n);
  k_fill2 <<<FILL_BLOCKS, 256, 0, stream>>>(bkt, bcnt, offs, deg, csr, cap);

  // Layer 1: h1 = relu(GCNagg(x) @ gcn1_w + b)           -> d_out (+hh)
  k_f2h<<<gC, 256, 0, stream>>>(x, dis, hh, n);            // hh = dis*x (pass-major)
  k_agg<0><<<gAgg, 256, 0, stream>>>(hh, offs, csr, dis, invd, bufA, n, nq);
  k_gemm1<true><<<gG, 256, 0, stream>>>(bufA, gcn1_w, gcn1_b, out, hh, n);

  // Layer 2: h2 = relu(mean(h1)@Wl + bl + h1@Wr + h1)    -> bufB (+hh)
  k_agg<1><<<gAgg, 256, 0, stream>>>(hh, offs, csr, dis, invd, bufA, n, nq);
  k_gemm_dual<true><<<gG, 256, 0, stream>>>(bufA, out, sage1_lw, sage1_rw, sage1_lb, bufB, hh, n);

  // Layer 3 (fused): hh = dis*relu((mean(h2)@Wl2+bl2+h2@Wr2+h2)@lin_w+lin_b)
  k_agg<1><<<gAgg, 256, 0, stream>>>(hh, offs, csr, dis, invd, bufA, n, nq);
  k_gemm_tri<<<gG, 256, 0, stream>>>(bufA, bufB, sage2_lw, sage2_rw, sage2_lb,
                                     lin_w, lin_b, dis, hh, n);

  // Layer 4: out = GCNagg(h4) @ gcn2_w + gcn2_b          -> d_out
  k_agg<0><<<gAgg, 256, 0, stream>>>(hh, offs, csr, dis, invd, bufA, n, nq);
  k_gemm1<false><<<gG, 256, 0, stream>>>(bufA, gcn2_w, gcn2_b, out, (ushort*)nullptr, n);
}